// Round 14
// baseline (139.080 us; speedup 1.0000x reference)
//
#include <hip/hip_runtime.h>

#define NN 50000
#define NNP 50176        // NN padded to 196*256
#define NE 1000000
#define NBK 196          // dst buckets of 256 nodes
#define ESTRIDE 5888     // es2 bucket capacity: 5102 +7.4sigma +256 evenize pad
#define EPC 2048         // edges per place chunk (512 thr x 4)
#define NCH 489          // ceil(NE/EPC); last chunk = 576 edges

// fallback-path defs
#define EPB 1024
#define PB 977

// ================= place4: h0-init + MLP + chunk-local bucket-grouped write
// (R13-proven form, byte-identical)
__global__ __launch_bounds__(512)
void place4(const float* __restrict__ x,
            const float* __restrict__ ea,
            const int* __restrict__ src,
            const int* __restrict__ dst,
            const float* __restrict__ w1,
            const float* __restrict__ b1,
            const float* __restrict__ w2,
            const float* __restrict__ b2,
            uint2* __restrict__ es,
            int* __restrict__ ebase,
            float* __restrict__ hA) {
    __shared__ float sw1[192];
    __shared__ float sb1[64];
    __shared__ float sw2[64];
    __shared__ int hist[NBK];
    __shared__ int part[256];
    __shared__ int lexcl[NBK];
    __shared__ uint2 eLDS[EPC];        // 16 KB
    const int t = threadIdx.x;
    const int j = blockIdx.x;
    if (t < 192) sw1[t] = w1[t];
    if (t < 64) { sb1[t] = b1[t]; sw2[t] = w2[t]; }
    if (t < NBK) hist[t] = 0;
    {   // h0 init folded in (blocks 0..97 cover all nodes)
        int i = j * 512 + t;
        if (i < NN) hA[i] = x[5 * i + 2];
    }
    __syncthreads();
    const float bz = b2[0];
    const int e0 = j * EPC;
    const int myN = (NE - e0 < EPC) ? (NE - e0) : EPC;

    float ce[4];
    int dd[4], rr[4], ss[4];
#pragma unroll
    for (int k = 0; k < 4; ++k) {
        int p = k * 512 + t;
        dd[k] = -1;
        if (p < myN) {
            int e = e0 + p;
            float a0 = ea[3 * e + 0];
            float a1 = ea[3 * e + 1];
            float a2 = ea[3 * e + 2];
            float c0 = bz, c1 = 0.f, c2 = 0.f, c3 = 0.f;
#pragma unroll
            for (int kk = 0; kk < 64; kk += 4) {
                float h0 = fmaf(a0, sw1[kk+0], fmaf(a1, sw1[64+kk+0], fmaf(a2, sw1[128+kk+0], sb1[kk+0])));
                float h1 = fmaf(a0, sw1[kk+1], fmaf(a1, sw1[64+kk+1], fmaf(a2, sw1[128+kk+1], sb1[kk+1])));
                float h2 = fmaf(a0, sw1[kk+2], fmaf(a1, sw1[64+kk+2], fmaf(a2, sw1[128+kk+2], sb1[kk+2])));
                float h3 = fmaf(a0, sw1[kk+3], fmaf(a1, sw1[64+kk+3], fmaf(a2, sw1[128+kk+3], sb1[kk+3])));
                c0 = fmaf(fmaxf(h0, 0.f), sw2[kk+0], c0);
                c1 = fmaf(fmaxf(h1, 0.f), sw2[kk+1], c1);
                c2 = fmaf(fmaxf(h2, 0.f), sw2[kk+2], c2);
                c3 = fmaf(fmaxf(h3, 0.f), sw2[kk+3], c3);
            }
            ce[k] = (c0 + c1) + (c2 + c3);
            ss[k] = src[e];
            int d = dst[e];
            dd[k] = d;
            rr[k] = atomicAdd(&hist[d >> 8], 1);
        }
    }
    __syncthreads();
    // exclusive scan of hist over 196 buckets (threads 0..255, all barrier)
    int val = 0;
    if (t < 256) { val = (t < NBK) ? hist[t] : 0; part[t] = val; }
    __syncthreads();
    for (int off = 1; off < 256; off <<= 1) {
        int xv = 0, add = 0;
        if (t < 256) { xv = part[t]; if (t >= off) add = part[t - off]; }
        __syncthreads();
        if (t < 256) part[t] = xv + add;
        __syncthreads();
    }
    if (t < NBK) {
        int excl = part[t] - val;
        lexcl[t] = excl;
        ebase[j * NBK + t] = (excl << 16) | val;   // both <= 2048 < 65536
    }
    __syncthreads();
#pragma unroll
    for (int k = 0; k < 4; ++k) {
        if (dd[k] >= 0) {
            int d = dd[k];
            int pos = lexcl[d >> 8] + rr[k];       // dense in [0, myN)
            eLDS[pos] = make_uint2((unsigned)ss[k] | ((unsigned)(d & 255) << 17),
                                   __float_as_uint(ce[k]));
        }
    }
    __syncthreads();
    for (int p = t; p < myN; p += 512)             // linear streaming write
        es[e0 + p] = eLDS[p];
}

// ================= sortround1: gather + dst-sort + round 1 (fused) =========
// R13 structure + (a) LUT-accelerated chunk lookup: binary search (9 dep LDS
// reads/edge) replaced by lut[p>>5] + ~3-step linear scan; (b) per-node es2
// start offsets EVENIZED so round_csr can use aligned uint4 loads.
__global__ __launch_bounds__(1024)
void sortround1(const int* __restrict__ ebase,
                const uint2* __restrict__ es,
                uint2* __restrict__ es2,
                uint2* __restrict__ nodePtr,
                const float* __restrict__ hold,
                float* __restrict__ hnew,
                const float* __restrict__ root,
                const float* __restrict__ bias) {
    __shared__ int cbase[NCH + 1];   // exclusive scan of per-chunk run lens
    __shared__ int cex[NCH];         // run offset within each chunk
    __shared__ int lut[192];         // chunk index for each 32-slot window
    __shared__ int hist[256];
    __shared__ int partc[512];       // chunk-scan workspace (489 -> 512)
    __shared__ int part[256];
    __shared__ int cur[256];
    __shared__ float lagg[256];
    const int t = threadIdx.x;
    const int b = blockIdx.x;
    if (t < 256) { hist[t] = 0; lagg[t] = 0.f; }
    // load (excl,cnt) column and scan cnt over 489 chunks
    int c = 0;
    if (t < NCH) {
        int pk = ebase[t * NBK + b];
        cex[t] = pk >> 16;
        c = pk & 0xFFFF;
    }
    if (t < 512) partc[t] = (t < NCH) ? c : 0;
    __syncthreads();
    for (int off = 1; off < 512; off <<= 1) {
        int xv = 0, add = 0;
        if (t < 512) { xv = partc[t]; if (t >= off) add = partc[t - off]; }
        __syncthreads();
        if (t < 512) partc[t] = xv + add;
        __syncthreads();
    }
    if (t < NCH) cbase[t] = partc[t] - c;
    if (t == 0) cbase[NCH] = partc[NCH - 1];       // total C
    __syncthreads();
    const int C = cbase[NCH];                      // <= ~5400; reg slots 6144
    // build 32-slot LUT: lut[i] = largest j with cbase[j] <= i*32
    if (t < 192) {
        int tgt = t * 32;
        int lo = 0, hi = NCH - 1;
        while (lo < hi) { int mid = (lo + hi + 1) >> 1; if (cbase[mid] <= tgt) lo = mid; else hi = mid - 1; }
        lut[t] = lo;
    }
    __syncthreads();

    // flat gather into registers + EARLY h-gather (overlaps the scans below)
    uint2 v[6]; float hv[6]; bool m[6];
#pragma unroll
    for (int k = 0; k < 6; ++k) {
        int p = k * 1024 + t;
        m[k] = (p < C);
        if (m[k]) {
            int lo = lut[p >> 5];                  // short linear scan (~3)
            while (lo < NCH - 1 && cbase[lo + 1] <= p) ++lo;
            v[k] = es[lo * EPC + cex[lo] + (p - cbase[lo])];
            atomicAdd(&hist[(v[k].x >> 17) & 255], 1);
            hv[k] = hold[v[k].x & 0x1FFFF];
        }
    }
    __syncthreads();
    // scan EVENIZED hist over 256 node-slots (even starts -> uint4 rounds)
    int val = 0, ev = 0;
    if (t < 256) { val = hist[t]; ev = (val + 1) & ~1; part[t] = ev; }
    __syncthreads();
    for (int off = 1; off < 256; off <<= 1) {
        int xv = 0, add = 0;
        if (t < 256) { xv = part[t]; if (t >= off) add = part[t - off]; }
        __syncthreads();
        if (t < 256) part[t] = xv + add;
        __syncthreads();
    }
    if (t < 256) {
        int excl = part[t] - ev;                   // even by construction
        cur[t] = excl;
        int ec = (excl < ESTRIDE) ? excl : ESTRIDE;
        nodePtr[b * 256 + t] = make_uint2((unsigned)(b * ESTRIDE + ec), (unsigned)val);
    }
    __syncthreads();
    // scatter to es2 + round-1 accumulate (h values already in registers)
#pragma unroll
    for (int k = 0; k < 6; ++k) {
        if (m[k]) {
            int key = (v[k].x >> 17) & 255;
            int pos = atomicAdd(&cur[key], 1);
            if (pos < ESTRIDE) es2[b * ESTRIDE + pos] = v[k];
            atomicAdd(&lagg[key], hv[k] * __uint_as_float(v[k].y));
        }
    }
    __syncthreads();
    if (t < 256) {
        int node = b * 256 + t;
        if (node < NN) {
            float inv = (val > 0) ? (1.0f / (float)val) : 0.f;
            hnew[node] = fmaxf(fmaf(hold[node], root[0], fmaf(lagg[t], inv, bias[0])), 0.f);
        }
    }
}

// ================= round_csr: vector-CSR, 4 lanes/row, uint4 loads ==========
// Row starts are even (evenized in sortround1) so es2 rows read as aligned
// uint4 (2 edges/load) - half the vmem instructions of the uint2 form.
// Batched: 3 uint4/lane covers deg<=24 (~85%); short tail loop beyond.
__global__ __launch_bounds__(256)
void round_csr(const uint2* __restrict__ nodePtr,
               const uint2* __restrict__ es2,
               const float* __restrict__ hold,
               float* __restrict__ hnew,
               const float* __restrict__ root,
               const float* __restrict__ bias) {
    int g = blockIdx.x * 256 + threadIdx.x;
    int row = g >> 2;
    int sub = g & 3;
    uint2 pk = nodePtr[row];
    int beg = (int)pk.x;               // even
    int len = (int)pk.y;
    const uint4* e4 = (const uint4*)es2;
    const int b4 = (beg >> 1) + sub;
    const int r0 = 2 * sub;            // rel edge of u.x in batch j: r0 + 8j
    bool n0 = (r0      < len), n0b = (r0 + 1  < len);
    bool n1 = (r0 + 8  < len), n1b = (r0 + 9  < len);
    bool n2 = (r0 + 16 < len), n2b = (r0 + 17 < len);
    uint4 u0, u1, u2;
    if (n0) u0 = e4[b4];
    if (n1) u1 = e4[b4 + 4];
    if (n2) u2 = e4[b4 + 8];
    float ga = 0.f, gb = 0.f, gc = 0.f, gd = 0.f, ge = 0.f, gf = 0.f;
    if (n0)  ga = hold[u0.x & 0x1FFFF];
    if (n0b) gb = hold[u0.z & 0x1FFFF];
    if (n1)  gc = hold[u1.x & 0x1FFFF];
    if (n1b) gd = hold[u1.z & 0x1FFFF];
    if (n2)  ge = hold[u2.x & 0x1FFFF];
    if (n2b) gf = hold[u2.z & 0x1FFFF];
    float acc = 0.f;
    if (n0)  acc += ga * __uint_as_float(u0.y);
    if (n0b) acc += gb * __uint_as_float(u0.w);
    if (n1)  acc += gc * __uint_as_float(u1.y);
    if (n1b) acc += gd * __uint_as_float(u1.w);
    if (n2)  acc += ge * __uint_as_float(u2.y);
    if (n2b) acc += gf * __uint_as_float(u2.w);
    for (int i = b4 + 12; ; i += 4) {              // tail: rel edges >= 24
        int rel = 2 * (i - (beg >> 1));
        if (rel >= len) break;
        uint4 u = e4[i];
        acc += hold[u.x & 0x1FFFF] * __uint_as_float(u.y);
        if (rel + 1 < len) acc += hold[u.z & 0x1FFFF] * __uint_as_float(u.w);
    }
    acc += __shfl_xor(acc, 1);
    acc += __shfl_xor(acc, 2);
    if (sub == 0 && row < NN) {
        float inv = (len > 0) ? (1.0f / (float)len) : 0.f;
        hnew[row] = fmaxf(fmaf(hold[row], root[0], fmaf(acc, inv, bias[0])), 0.f);
    }
}

// ================= fallback-path kernels (ws too small) ====================
__global__ void bucket_count(const int* __restrict__ dst, int* __restrict__ bcnt,
                             const float* __restrict__ x, float* __restrict__ h) {
    __shared__ int hist[NBK];
    int t = threadIdx.x;
    if (t < NBK) hist[t] = 0;
    __syncthreads();
    int gid = blockIdx.x * 256 + t;
    if (gid < NN) h[gid] = x[5 * gid + 2];
#pragma unroll
    for (int j = 0; j < 4; ++j) {
        int e = blockIdx.x * EPB + j * 256 + t;
        if (e < NE) atomicAdd(&hist[dst[e] >> 8], 1);
    }
    __syncthreads();
    if (t < NBK && hist[t]) atomicAdd(&bcnt[t], hist[t]);
}

__global__ void bucket_scan(const int* __restrict__ bcnt,
                            int* __restrict__ sBeg,
                            int* __restrict__ cursor,
                            int* __restrict__ sLim) {
    __shared__ int part[256];
    int t = threadIdx.x;
    int v = (t < NBK) ? ((bcnt[t] + 1) & ~1) : 0;   // round up to even
    part[t] = v;
    __syncthreads();
    for (int off = 1; off < 256; off <<= 1) {
        int x = part[t];
        int add = (t >= off) ? part[t - off] : 0;
        __syncthreads();
        part[t] = x + add;
        __syncthreads();
    }
    if (t < NBK) {
        int excl = part[t] - v;
        sBeg[t] = excl;
        cursor[t] = excl;
        sLim[t] = 0x7FFFFFFF;   // exact counts: overflow impossible
    }
}

__global__ void place_kernel(const float* __restrict__ ea,
                             const int* __restrict__ src,
                             const int* __restrict__ dst,
                             const float* __restrict__ w1,
                             const float* __restrict__ b1,
                             const float* __restrict__ w2,
                             const float* __restrict__ b2,
                             const int* __restrict__ sLim,
                             int* __restrict__ cursor,
                             uint2* __restrict__ es,
                             int dumpbase) {
    __shared__ float sw1[192];
    __shared__ float sb1[64];
    __shared__ float sw2[64];
    __shared__ float sce[EPB];
    __shared__ int hist[NBK];
    __shared__ int hbase[NBK];
    int t = threadIdx.x;
    if (t < 192) sw1[t] = w1[t];
    if (t < 64) { sb1[t] = b1[t]; sw2[t] = w2[t]; }
    if (t < NBK) hist[t] = 0;
    __syncthreads();

    int r[4], dd[4];
#pragma unroll
    for (int j = 0; j < 4; ++j) {
        int e = blockIdx.x * EPB + j * 256 + t;
        dd[j] = -1;
        if (e < NE) {
            float a0 = ea[3 * e + 0];
            float a1 = ea[3 * e + 1];
            float a2 = ea[3 * e + 2];
            float c0 = b2[0], c1 = 0.f, c2 = 0.f, c3 = 0.f;
#pragma unroll
            for (int k = 0; k < 64; k += 4) {
                float h0 = fmaf(a0, sw1[k+0], fmaf(a1, sw1[64+k+0], fmaf(a2, sw1[128+k+0], sb1[k+0])));
                float h1 = fmaf(a0, sw1[k+1], fmaf(a1, sw1[64+k+1], fmaf(a2, sw1[128+k+1], sb1[k+1])));
                float h2 = fmaf(a0, sw1[k+2], fmaf(a1, sw1[64+k+2], fmaf(a2, sw1[128+k+2], sb1[k+2])));
                float h3 = fmaf(a0, sw1[k+3], fmaf(a1, sw1[64+k+3], fmaf(a2, sw1[128+k+3], sb1[k+3])));
                c0 = fmaf(fmaxf(h0, 0.f), sw2[k+0], c0);
                c1 = fmaf(fmaxf(h1, 0.f), sw2[k+1], c1);
                c2 = fmaf(fmaxf(h2, 0.f), sw2[k+2], c2);
                c3 = fmaf(fmaxf(h3, 0.f), sw2[k+3], c3);
            }
            sce[j * 256 + t] = (c0 + c1) + (c2 + c3);
            int d = dst[e];
            dd[j] = d;
            r[j] = atomicAdd(&hist[d >> 8], 1);
        }
    }
    __syncthreads();
    if (t < NBK) { int hv = hist[t]; if (hv) hbase[t] = atomicAdd(&cursor[t], hv); }
    __syncthreads();
#pragma unroll
    for (int j = 0; j < 4; ++j) {
        int e = blockIdx.x * EPB + j * 256 + t;
        if (e < NE) {
            int d = dd[j];
            int b = d >> 8;
            int pos = hbase[b] + r[j];
            if (pos >= sLim[b]) pos = dumpbase + (t & 63);
            unsigned pack = (unsigned)src[e] | ((unsigned)(d & 255) << 17);
            es[pos] = make_uint2(pack, __float_as_uint(sce[j * 256 + t]));
        }
    }
}

template<int FIRST>
__global__ __launch_bounds__(1024)
void round_fused_fb(const int* __restrict__ sBeg,
                    const int* __restrict__ sEnd,
                    const int* __restrict__ sLim,
                    const uint2* __restrict__ es,
                    const float* __restrict__ hold,
                    float* __restrict__ hnew,
                    float* __restrict__ invdeg,
                    const float* __restrict__ root,
                    const float* __restrict__ bias) {
    __shared__ float lagg[256];
    __shared__ int ldeg[256];
    int t = threadIdx.x;
    int b = blockIdx.x;
    if (t < 256) { lagg[t] = 0.f; if (FIRST) ldeg[t] = 0; }
    __syncthreads();
    int s0 = sBeg[b];
    int s1 = sEnd[b];
    { int cap = sLim[b]; if (s1 > cap) s1 = cap; }
    const uint4* es4 = (const uint4*)es;
    for (int p = s0 + t * 2; p < s1; p += 2048) {
        uint4 v = es4[p >> 1];
        {
            int sidx = v.x & 0x1FFFF;
            int dl = (v.x >> 17) & 255;
            atomicAdd(&lagg[dl], hold[sidx] * __uint_as_float(v.y));
            if (FIRST) atomicAdd(&ldeg[dl], 1);
        }
        if (p + 1 < s1) {
            int sidx = v.z & 0x1FFFF;
            int dl = (v.z >> 17) & 255;
            atomicAdd(&lagg[dl], hold[sidx] * __uint_as_float(v.w));
            if (FIRST) atomicAdd(&ldeg[dl], 1);
        }
    }
    __syncthreads();
    if (t < 256) {
        int node = b * 256 + t;
        if (node < NN) {
            float inv;
            if (FIRST) {
                int d = ldeg[t];
                inv = (d > 0) ? (1.0f / (float)d) : 0.f;
                invdeg[node] = inv;
            } else {
                inv = invdeg[node];
            }
            hnew[node] = fmaxf(fmaf(hold[node], root[0], fmaf(lagg[t], inv, bias[0])), 0.f);
        }
    }
}

// ================= launch =================

extern "C" void kernel_launch(void* const* d_in, const int* in_sizes, int n_in,
                              void* d_out, int out_size, void* d_ws, size_t ws_size,
                              hipStream_t stream) {
    const float* x    = (const float*)d_in[0];
    const int*   ei   = (const int*)d_in[1];
    const float* ea   = (const float*)d_in[2];
    const float* w1   = (const float*)d_in[3];
    const float* b1   = (const float*)d_in[4];
    const float* w2   = (const float*)d_in[5];
    const float* b2   = (const float*)d_in[6];
    const float* root = (const float*)d_in[7];
    const float* bias = (const float*)d_in[8];

    const int* src = ei;
    const int* dst = ei + NE;
    float* out = (float*)d_out;

    const size_t esN  = (size_t)NCH * EPC;                // chunked es (dense)
    const size_t es2N = (size_t)NBK * ESTRIDE + 64;       // sorted es2 + dump
    const size_t needFixed = esN * 8 + es2N * 8
                           + (size_t)(NCH * NBK) * 4      // ebase
                           + (size_t)NNP * 8              // nodePtr
                           + (size_t)NN * 4 * 2;          // hA, hB

    if (ws_size >= needFixed) {
        // -------- fixed path: 5 dispatches, no memset --------
        uint2* es      = (uint2*)d_ws;
        uint2* es2     = es + esN;
        int*   ebase   = (int*)(es2 + es2N);
        uint2* nodePtr = (uint2*)(ebase + (size_t)NCH * NBK);
        float* hA      = (float*)(nodePtr + NNP);
        float* hB      = hA + NN;

        place4<<<NCH, 512, 0, stream>>>(x, ea, src, dst, w1, b1, w2, b2,
                                        es, ebase, hA);
        sortround1<<<NBK, 1024, 0, stream>>>(ebase, es, es2, nodePtr,
                                             hA, hB, root, bias);
        const int gR = NNP * 4 / 256;    // 784 blocks, 4 lanes/row
        round_csr<<<gR, 256, 0, stream>>>(nodePtr, es2, hB, hA, root, bias);
        round_csr<<<gR, 256, 0, stream>>>(nodePtr, es2, hA, hB, root, bias);
        round_csr<<<gR, 256, 0, stream>>>(nodePtr, es2, hB, out, root, bias);
    } else {
        // -------- fallback: exact counts via count+scan --------
        uint2* es     = (uint2*)d_ws;                    // NE + NBK entries
        int*   bcnt   = (int*)(es + NE + NBK);
        int*   cursor = bcnt + NBK;
        int*   sBeg   = cursor + NBK;
        int*   sLim   = sBeg + NBK;
        float* invdeg = (float*)(sLim + NBK);
        float* hB     = invdeg + NN;
        float* h      = out;

        hipMemsetAsync(bcnt, 0, NBK * 4, stream);
        bucket_count<<<PB, 256, 0, stream>>>(dst, bcnt, x, h);
        bucket_scan<<<1, 256, 0, stream>>>(bcnt, sBeg, cursor, sLim);
        place_kernel<<<PB, 256, 0, stream>>>(ea, src, dst, w1, b1, w2, b2,
                                             sLim, cursor, es, 0);
        round_fused_fb<1><<<NBK, 1024, 0, stream>>>(sBeg, cursor, sLim, es, h,  hB, invdeg, root, bias);
        round_fused_fb<0><<<NBK, 1024, 0, stream>>>(sBeg, cursor, sLim, es, hB, h,  invdeg, root, bias);
        round_fused_fb<0><<<NBK, 1024, 0, stream>>>(sBeg, cursor, sLim, es, h,  hB, invdeg, root, bias);
        round_fused_fb<0><<<NBK, 1024, 0, stream>>>(sBeg, cursor, sLim, es, hB, h,  invdeg, root, bias);
    }
}

// Round 15
// 134.555 us; speedup vs baseline: 1.0336x; 1.0336x over previous
//
#include <hip/hip_runtime.h>

#define NN 50000
#define NNP 50176        // NN padded to 196*256
#define NE 1000000
#define NBK 196          // dst buckets of 256 nodes
#define ESTRIDE 5632     // es2 bucket capacity: mean 5102, sigma ~71 -> +7.4 sigma
#define EPC 2048         // edges per place chunk (512 thr x 4)
#define NCH 489          // ceil(NE/EPC); last chunk = 576 edges

// fallback-path defs
#define EPB 1024
#define PB 977

// ================= place4: h0-init + MLP + chunk-local bucket-grouped write
// 489 blocks x 512 threads: ~1.9 blocks/CU so no idle CUs, finer tail, and
// the 512-thr launch bound doubles the VGPR cap to 128 (R10/R11: at 1024 thr
// the 64-VGPR cap spilled every multi-edge register-cached variant).
// Scalar loads + streaming per-edge MLP (proven); LDS counting-sort by dst
// bucket; ONE linear streaming write. ebase[j*196+b]=(excl<<16)|cnt.
__global__ __launch_bounds__(512)
void place4(const float* __restrict__ x,
            const float* __restrict__ ea,
            const int* __restrict__ src,
            const int* __restrict__ dst,
            const float* __restrict__ w1,
            const float* __restrict__ b1,
            const float* __restrict__ w2,
            const float* __restrict__ b2,
            uint2* __restrict__ es,
            int* __restrict__ ebase,
            float* __restrict__ hA) {
    __shared__ float sw1[192];
    __shared__ float sb1[64];
    __shared__ float sw2[64];
    __shared__ int hist[NBK];
    __shared__ int part[256];
    __shared__ int lexcl[NBK];
    __shared__ uint2 eLDS[EPC];        // 16 KB
    const int t = threadIdx.x;
    const int j = blockIdx.x;
    if (t < 192) sw1[t] = w1[t];
    if (t < 64) { sb1[t] = b1[t]; sw2[t] = w2[t]; }
    if (t < NBK) hist[t] = 0;
    {   // h0 init folded in (blocks 0..97 cover all nodes)
        int i = j * 512 + t;
        if (i < NN) hA[i] = x[5 * i + 2];
    }
    __syncthreads();
    const float bz = b2[0];
    const int e0 = j * EPC;
    const int myN = (NE - e0 < EPC) ? (NE - e0) : EPC;

    float ce[4];
    int dd[4], rr[4], ss[4];
#pragma unroll
    for (int k = 0; k < 4; ++k) {
        int p = k * 512 + t;
        dd[k] = -1;
        if (p < myN) {
            int e = e0 + p;
            float a0 = ea[3 * e + 0];
            float a1 = ea[3 * e + 1];
            float a2 = ea[3 * e + 2];
            float c0 = bz, c1 = 0.f, c2 = 0.f, c3 = 0.f;
#pragma unroll
            for (int kk = 0; kk < 64; kk += 4) {
                float h0 = fmaf(a0, sw1[kk+0], fmaf(a1, sw1[64+kk+0], fmaf(a2, sw1[128+kk+0], sb1[kk+0])));
                float h1 = fmaf(a0, sw1[kk+1], fmaf(a1, sw1[64+kk+1], fmaf(a2, sw1[128+kk+1], sb1[kk+1])));
                float h2 = fmaf(a0, sw1[kk+2], fmaf(a1, sw1[64+kk+2], fmaf(a2, sw1[128+kk+2], sb1[kk+2])));
                float h3 = fmaf(a0, sw1[kk+3], fmaf(a1, sw1[64+kk+3], fmaf(a2, sw1[128+kk+3], sb1[kk+3])));
                c0 = fmaf(fmaxf(h0, 0.f), sw2[kk+0], c0);
                c1 = fmaf(fmaxf(h1, 0.f), sw2[kk+1], c1);
                c2 = fmaf(fmaxf(h2, 0.f), sw2[kk+2], c2);
                c3 = fmaf(fmaxf(h3, 0.f), sw2[kk+3], c3);
            }
            ce[k] = (c0 + c1) + (c2 + c3);
            ss[k] = src[e];
            int d = dst[e];
            dd[k] = d;
            rr[k] = atomicAdd(&hist[d >> 8], 1);
        }
    }
    __syncthreads();
    // exclusive scan of hist over 196 buckets (threads 0..255, all barrier)
    int val = 0;
    if (t < 256) { val = (t < NBK) ? hist[t] : 0; part[t] = val; }
    __syncthreads();
    for (int off = 1; off < 256; off <<= 1) {
        int xv = 0, add = 0;
        if (t < 256) { xv = part[t]; if (t >= off) add = part[t - off]; }
        __syncthreads();
        if (t < 256) part[t] = xv + add;
        __syncthreads();
    }
    if (t < NBK) {
        int excl = part[t] - val;
        lexcl[t] = excl;
        ebase[j * NBK + t] = (excl << 16) | val;   // both <= 2048 < 65536
    }
    __syncthreads();
#pragma unroll
    for (int k = 0; k < 4; ++k) {
        if (dd[k] >= 0) {
            int d = dd[k];
            int pos = lexcl[d >> 8] + rr[k];       // dense in [0, myN)
            eLDS[pos] = make_uint2((unsigned)ss[k] | ((unsigned)(d & 255) << 17),
                                   __float_as_uint(ce[k]));
        }
    }
    __syncthreads();
    for (int p = t; p < myN; p += 512)             // linear streaming write
        es[e0 + p] = eLDS[p];
}

// ================= sortround1: gather + dst-sort + round 1 (fused) =========
// Block b gathers bucket b's runs from all 489 chunks (flat index + binary
// search over run bases), counting-sorts by dst&255, writes es2 + nodePtr
// for rounds 2..4, and performs round 1 from the register-held entries.
// h-gathers hoisted into the gather loop so their latency overlaps the scans.
__global__ __launch_bounds__(1024)
void sortround1(const int* __restrict__ ebase,
                const uint2* __restrict__ es,
                uint2* __restrict__ es2,
                uint2* __restrict__ nodePtr,
                const float* __restrict__ hold,
                float* __restrict__ hnew,
                const float* __restrict__ root,
                const float* __restrict__ bias) {
    __shared__ int cbase[NCH + 1];   // exclusive scan of per-chunk run lens
    __shared__ int cex[NCH];         // run offset within each chunk
    __shared__ int hist[256];
    __shared__ int partc[512];       // chunk-scan workspace (489 -> 512)
    __shared__ int part[256];
    __shared__ int cur[256];
    __shared__ float lagg[256];
    const int t = threadIdx.x;
    const int b = blockIdx.x;
    if (t < 256) { hist[t] = 0; lagg[t] = 0.f; }
    // load (excl,cnt) column and scan cnt over 489 chunks
    int c = 0;
    if (t < NCH) {
        int pk = ebase[t * NBK + b];
        cex[t] = pk >> 16;
        c = pk & 0xFFFF;
    }
    if (t < 512) partc[t] = (t < NCH) ? c : 0;
    __syncthreads();
    for (int off = 1; off < 512; off <<= 1) {
        int xv = 0, add = 0;
        if (t < 512) { xv = partc[t]; if (t >= off) add = partc[t - off]; }
        __syncthreads();
        if (t < 512) partc[t] = xv + add;
        __syncthreads();
    }
    if (t < NCH) cbase[t] = partc[t] - c;
    if (t == 0) cbase[NCH] = partc[NCH - 1];       // total C
    __syncthreads();
    const int C = cbase[NCH];                      // <= ~5400; reg slots 6144

    // flat gather into registers + EARLY h-gather (overlaps the scans below)
    uint2 v[6]; float hv[6]; bool m[6];
#pragma unroll
    for (int k = 0; k < 6; ++k) {
        int p = k * 1024 + t;
        m[k] = (p < C);
        if (m[k]) {
            int lo = 0, hi = NCH - 1;              // largest j: cbase[j] <= p
            while (lo < hi) { int mid = (lo + hi + 1) >> 1; if (cbase[mid] <= p) lo = mid; else hi = mid - 1; }
            v[k] = es[lo * EPC + cex[lo] + (p - cbase[lo])];
            atomicAdd(&hist[(v[k].x >> 17) & 255], 1);
            hv[k] = hold[v[k].x & 0x1FFFF];
        }
    }
    __syncthreads();
    // scan hist over 256 node-slots
    int val = 0;
    if (t < 256) { val = hist[t]; part[t] = val; }
    __syncthreads();
    for (int off = 1; off < 256; off <<= 1) {
        int xv = 0, add = 0;
        if (t < 256) { xv = part[t]; if (t >= off) add = part[t - off]; }
        __syncthreads();
        if (t < 256) part[t] = xv + add;
        __syncthreads();
    }
    if (t < 256) {
        int excl = part[t] - val;
        cur[t] = excl;
        int ec = (excl < ESTRIDE) ? excl : ESTRIDE;
        nodePtr[b * 256 + t] = make_uint2((unsigned)(b * ESTRIDE + ec), (unsigned)val);
    }
    __syncthreads();
    // scatter to es2 + round-1 accumulate (h values already in registers)
#pragma unroll
    for (int k = 0; k < 6; ++k) {
        if (m[k]) {
            int key = (v[k].x >> 17) & 255;
            int pos = atomicAdd(&cur[key], 1);
            if (pos < ESTRIDE) es2[b * ESTRIDE + pos] = v[k];
            atomicAdd(&lagg[key], hv[k] * __uint_as_float(v[k].y));
        }
    }
    __syncthreads();
    if (t < 256) {
        int node = b * 256 + t;
        if (node < NN) {
            float inv = (val > 0) ? (1.0f / (float)val) : 0.f;
            hnew[node] = fmaxf(fmaf(hold[node], root[0], fmaf(lagg[t], inv, bias[0])), 0.f);
        }
    }
}

// ================= round_csr: vector-CSR, 8 lanes/row, batched issue ========
// Up to 4 masked es2 loads issued together, then 4 h-gathers, then FMAs.
// Covers deg<=32 (mean 20, sigma 4.5); rare tail loop for deg>32.
__global__ __launch_bounds__(256)
void round_csr(const uint2* __restrict__ nodePtr,
               const uint2* __restrict__ es2,
               const float* __restrict__ hold,
               float* __restrict__ hnew,
               const float* __restrict__ root,
               const float* __restrict__ bias) {
    int g = blockIdx.x * 256 + threadIdx.x;
    int row = g >> 3;
    int sub = g & 7;
    uint2 pk = nodePtr[row];
    int beg = (int)pk.x;
    int len = (int)pk.y;
    bool m0 = (sub      < len), m1 = (sub + 8  < len);
    bool m2 = (sub + 16 < len), m3 = (sub + 24 < len);
    uint2 v0, v1, v2, v3;
    if (m0) v0 = es2[beg + sub];
    if (m1) v1 = es2[beg + sub + 8];
    if (m2) v2 = es2[beg + sub + 16];
    if (m3) v3 = es2[beg + sub + 24];
    float g0 = 0.f, g1 = 0.f, g2 = 0.f, g3 = 0.f;
    if (m0) g0 = hold[v0.x & 0x1FFFF];
    if (m1) g1 = hold[v1.x & 0x1FFFF];
    if (m2) g2 = hold[v2.x & 0x1FFFF];
    if (m3) g3 = hold[v3.x & 0x1FFFF];
    float acc = 0.f;
    if (m0) acc += g0 * __uint_as_float(v0.y);
    if (m1) acc += g1 * __uint_as_float(v1.y);
    if (m2) acc += g2 * __uint_as_float(v2.y);
    if (m3) acc += g3 * __uint_as_float(v3.y);
    for (int k = sub + 32; k < len; k += 8) {      // rare (deg>32: ~0.4%)
        uint2 v = es2[beg + k];
        acc += hold[v.x & 0x1FFFF] * __uint_as_float(v.y);
    }
    acc += __shfl_xor(acc, 1);
    acc += __shfl_xor(acc, 2);
    acc += __shfl_xor(acc, 4);
    if (sub == 0 && row < NN) {
        float inv = (len > 0) ? (1.0f / (float)len) : 0.f;
        hnew[row] = fmaxf(fmaf(hold[row], root[0], fmaf(acc, inv, bias[0])), 0.f);
    }
}

// ================= fallback-path kernels (ws too small) ====================
__global__ void bucket_count(const int* __restrict__ dst, int* __restrict__ bcnt,
                             const float* __restrict__ x, float* __restrict__ h) {
    __shared__ int hist[NBK];
    int t = threadIdx.x;
    if (t < NBK) hist[t] = 0;
    __syncthreads();
    int gid = blockIdx.x * 256 + t;
    if (gid < NN) h[gid] = x[5 * gid + 2];
#pragma unroll
    for (int j = 0; j < 4; ++j) {
        int e = blockIdx.x * EPB + j * 256 + t;
        if (e < NE) atomicAdd(&hist[dst[e] >> 8], 1);
    }
    __syncthreads();
    if (t < NBK && hist[t]) atomicAdd(&bcnt[t], hist[t]);
}

__global__ void bucket_scan(const int* __restrict__ bcnt,
                            int* __restrict__ sBeg,
                            int* __restrict__ cursor,
                            int* __restrict__ sLim) {
    __shared__ int part[256];
    int t = threadIdx.x;
    int v = (t < NBK) ? ((bcnt[t] + 1) & ~1) : 0;   // round up to even
    part[t] = v;
    __syncthreads();
    for (int off = 1; off < 256; off <<= 1) {
        int x = part[t];
        int add = (t >= off) ? part[t - off] : 0;
        __syncthreads();
        part[t] = x + add;
        __syncthreads();
    }
    if (t < NBK) {
        int excl = part[t] - v;
        sBeg[t] = excl;
        cursor[t] = excl;
        sLim[t] = 0x7FFFFFFF;   // exact counts: overflow impossible
    }
}

__global__ void place_kernel(const float* __restrict__ ea,
                             const int* __restrict__ src,
                             const int* __restrict__ dst,
                             const float* __restrict__ w1,
                             const float* __restrict__ b1,
                             const float* __restrict__ w2,
                             const float* __restrict__ b2,
                             const int* __restrict__ sLim,
                             int* __restrict__ cursor,
                             uint2* __restrict__ es,
                             int dumpbase) {
    __shared__ float sw1[192];
    __shared__ float sb1[64];
    __shared__ float sw2[64];
    __shared__ float sce[EPB];
    __shared__ int hist[NBK];
    __shared__ int hbase[NBK];
    int t = threadIdx.x;
    if (t < 192) sw1[t] = w1[t];
    if (t < 64) { sb1[t] = b1[t]; sw2[t] = w2[t]; }
    if (t < NBK) hist[t] = 0;
    __syncthreads();

    int r[4], dd[4];
#pragma unroll
    for (int j = 0; j < 4; ++j) {
        int e = blockIdx.x * EPB + j * 256 + t;
        dd[j] = -1;
        if (e < NE) {
            float a0 = ea[3 * e + 0];
            float a1 = ea[3 * e + 1];
            float a2 = ea[3 * e + 2];
            float c0 = b2[0], c1 = 0.f, c2 = 0.f, c3 = 0.f;
#pragma unroll
            for (int k = 0; k < 64; k += 4) {
                float h0 = fmaf(a0, sw1[k+0], fmaf(a1, sw1[64+k+0], fmaf(a2, sw1[128+k+0], sb1[k+0])));
                float h1 = fmaf(a0, sw1[k+1], fmaf(a1, sw1[64+k+1], fmaf(a2, sw1[128+k+1], sb1[k+1])));
                float h2 = fmaf(a0, sw1[k+2], fmaf(a1, sw1[64+k+2], fmaf(a2, sw1[128+k+2], sb1[k+2])));
                float h3 = fmaf(a0, sw1[k+3], fmaf(a1, sw1[64+k+3], fmaf(a2, sw1[128+k+3], sb1[k+3])));
                c0 = fmaf(fmaxf(h0, 0.f), sw2[k+0], c0);
                c1 = fmaf(fmaxf(h1, 0.f), sw2[k+1], c1);
                c2 = fmaf(fmaxf(h2, 0.f), sw2[k+2], c2);
                c3 = fmaf(fmaxf(h3, 0.f), sw2[k+3], c3);
            }
            sce[j * 256 + t] = (c0 + c1) + (c2 + c3);
            int d = dst[e];
            dd[j] = d;
            r[j] = atomicAdd(&hist[d >> 8], 1);
        }
    }
    __syncthreads();
    if (t < NBK) { int hv = hist[t]; if (hv) hbase[t] = atomicAdd(&cursor[t], hv); }
    __syncthreads();
#pragma unroll
    for (int j = 0; j < 4; ++j) {
        int e = blockIdx.x * EPB + j * 256 + t;
        if (e < NE) {
            int d = dd[j];
            int b = d >> 8;
            int pos = hbase[b] + r[j];
            if (pos >= sLim[b]) pos = dumpbase + (t & 63);
            unsigned pack = (unsigned)src[e] | ((unsigned)(d & 255) << 17);
            es[pos] = make_uint2(pack, __float_as_uint(sce[j * 256 + t]));
        }
    }
}

template<int FIRST>
__global__ __launch_bounds__(1024)
void round_fused_fb(const int* __restrict__ sBeg,
                    const int* __restrict__ sEnd,
                    const int* __restrict__ sLim,
                    const uint2* __restrict__ es,
                    const float* __restrict__ hold,
                    float* __restrict__ hnew,
                    float* __restrict__ invdeg,
                    const float* __restrict__ root,
                    const float* __restrict__ bias) {
    __shared__ float lagg[256];
    __shared__ int ldeg[256];
    int t = threadIdx.x;
    int b = blockIdx.x;
    if (t < 256) { lagg[t] = 0.f; if (FIRST) ldeg[t] = 0; }
    __syncthreads();
    int s0 = sBeg[b];
    int s1 = sEnd[b];
    { int cap = sLim[b]; if (s1 > cap) s1 = cap; }
    const uint4* es4 = (const uint4*)es;
    for (int p = s0 + t * 2; p < s1; p += 2048) {
        uint4 v = es4[p >> 1];
        {
            int sidx = v.x & 0x1FFFF;
            int dl = (v.x >> 17) & 255;
            atomicAdd(&lagg[dl], hold[sidx] * __uint_as_float(v.y));
            if (FIRST) atomicAdd(&ldeg[dl], 1);
        }
        if (p + 1 < s1) {
            int sidx = v.z & 0x1FFFF;
            int dl = (v.z >> 17) & 255;
            atomicAdd(&lagg[dl], hold[sidx] * __uint_as_float(v.w));
            if (FIRST) atomicAdd(&ldeg[dl], 1);
        }
    }
    __syncthreads();
    if (t < 256) {
        int node = b * 256 + t;
        if (node < NN) {
            float inv;
            if (FIRST) {
                int d = ldeg[t];
                inv = (d > 0) ? (1.0f / (float)d) : 0.f;
                invdeg[node] = inv;
            } else {
                inv = invdeg[node];
            }
            hnew[node] = fmaxf(fmaf(hold[node], root[0], fmaf(lagg[t], inv, bias[0])), 0.f);
        }
    }
}

// ================= launch =================

extern "C" void kernel_launch(void* const* d_in, const int* in_sizes, int n_in,
                              void* d_out, int out_size, void* d_ws, size_t ws_size,
                              hipStream_t stream) {
    const float* x    = (const float*)d_in[0];
    const int*   ei   = (const int*)d_in[1];
    const float* ea   = (const float*)d_in[2];
    const float* w1   = (const float*)d_in[3];
    const float* b1   = (const float*)d_in[4];
    const float* w2   = (const float*)d_in[5];
    const float* b2   = (const float*)d_in[6];
    const float* root = (const float*)d_in[7];
    const float* bias = (const float*)d_in[8];

    const int* src = ei;
    const int* dst = ei + NE;
    float* out = (float*)d_out;

    const size_t esN  = (size_t)NCH * EPC;                // chunked es (dense)
    const size_t es2N = (size_t)NBK * ESTRIDE + 64;       // sorted es2 + dump
    const size_t needFixed = esN * 8 + es2N * 8
                           + (size_t)(NCH * NBK) * 4      // ebase
                           + (size_t)NNP * 8              // nodePtr
                           + (size_t)NN * 4 * 2;          // hA, hB

    if (ws_size >= needFixed) {
        // -------- fixed path: 5 dispatches, no memset --------
        uint2* es      = (uint2*)d_ws;
        uint2* es2     = es + esN;
        int*   ebase   = (int*)(es2 + es2N);
        uint2* nodePtr = (uint2*)(ebase + (size_t)NCH * NBK);
        float* hA      = (float*)(nodePtr + NNP);
        float* hB      = hA + NN;

        place4<<<NCH, 512, 0, stream>>>(x, ea, src, dst, w1, b1, w2, b2,
                                        es, ebase, hA);
        sortround1<<<NBK, 1024, 0, stream>>>(ebase, es, es2, nodePtr,
                                             hA, hB, root, bias);
        const int gR = NNP * 8 / 256;    // 1568 blocks, 8 lanes/row
        round_csr<<<gR, 256, 0, stream>>>(nodePtr, es2, hB, hA, root, bias);
        round_csr<<<gR, 256, 0, stream>>>(nodePtr, es2, hA, hB, root, bias);
        round_csr<<<gR, 256, 0, stream>>>(nodePtr, es2, hB, out, root, bias);
    } else {
        // -------- fallback: exact counts via count+scan --------
        uint2* es     = (uint2*)d_ws;                    // NE + NBK entries
        int*   bcnt   = (int*)(es + NE + NBK);
        int*   cursor = bcnt + NBK;
        int*   sBeg   = cursor + NBK;
        int*   sLim   = sBeg + NBK;
        float* invdeg = (float*)(sLim + NBK);
        float* hB     = invdeg + NN;
        float* h      = out;

        hipMemsetAsync(bcnt, 0, NBK * 4, stream);
        bucket_count<<<PB, 256, 0, stream>>>(dst, bcnt, x, h);
        bucket_scan<<<1, 256, 0, stream>>>(bcnt, sBeg, cursor, sLim);
        place_kernel<<<PB, 256, 0, stream>>>(ea, src, dst, w1, b1, w2, b2,
                                             sLim, cursor, es, 0);
        round_fused_fb<1><<<NBK, 1024, 0, stream>>>(sBeg, cursor, sLim, es, h,  hB, invdeg, root, bias);
        round_fused_fb<0><<<NBK, 1024, 0, stream>>>(sBeg, cursor, sLim, es, hB, h,  invdeg, root, bias);
        round_fused_fb<0><<<NBK, 1024, 0, stream>>>(sBeg, cursor, sLim, es, h,  hB, invdeg, root, bias);
        round_fused_fb<0><<<NBK, 1024, 0, stream>>>(sBeg, cursor, sLim, es, hB, h,  invdeg, root, bias);
    }
}